// Round 3
// baseline (622.714 us; speedup 1.0000x reference)
//
#include <hip/hip_runtime.h>

#define DIM 128
#define NOUT 40
#define ROWS 64   // nodes per GEMM block
#define HPAD 2    // Hl stride 130: scalar H-reads spread over 4 banks (vs 2 at pad 4)

// ============ CSR build (once per launch) ============

__global__ __launch_bounds__(256) void hist_kernel(
    const int* __restrict__ dst, int* __restrict__ deg, int n_edges)
{
    int e = blockIdx.x * 256 + threadIdx.x;
    if (e < n_edges) atomicAdd(&deg[dst[e]], 1);
}

// --- hierarchical scan: reduce(1024/block) -> scan partials (1 block) -> apply ---
__global__ __launch_bounds__(256) void reduce_kernel(
    const int* __restrict__ deg, int* __restrict__ bsum, int n)
{
    int t = threadIdx.x;
    int base = blockIdx.x * 1024 + t;
    int s = 0;
    #pragma unroll
    for (int i = 0; i < 4; ++i) { int idx = base + i * 256; s += (idx < n) ? deg[idx] : 0; }
    for (int o = 32; o; o >>= 1) s += __shfl_down(s, o, 64);
    __shared__ int l[4];
    if ((t & 63) == 0) l[t >> 6] = s;
    __syncthreads();
    if (t == 0) bsum[blockIdx.x] = l[0] + l[1] + l[2] + l[3];
}

__global__ __launch_bounds__(128) void scan_sums_kernel(
    int* __restrict__ bsum, int nb, int* __restrict__ off_n)
{
    __shared__ int l[128];
    int t = threadIdx.x;
    int c = (nb + 127) >> 7;
    int b = t * c, e = min(b + c, nb);
    int s = 0;
    for (int i = b; i < e; ++i) s += bsum[i];
    l[t] = s;
    __syncthreads();
    for (int d = 1; d < 128; d <<= 1) {
        int u = (t >= d) ? l[t - d] : 0;
        __syncthreads();
        l[t] += u;
        __syncthreads();
    }
    int pre = l[t] - s;   // exclusive
    for (int i = b; i < e; ++i) { int v = bsum[i]; bsum[i] = pre; pre += v; }
    if (t == 127) *off_n = l[127];
}

__global__ __launch_bounds__(256) void apply_kernel(
    const int* __restrict__ deg, const int* __restrict__ bsum,
    int* __restrict__ off, int n)
{
    int t = threadIdx.x;
    int i0 = blockIdx.x * 1024 + t * 4;
    int d0 = (i0     < n) ? deg[i0]     : 0;
    int d1 = (i0 + 1 < n) ? deg[i0 + 1] : 0;
    int d2 = (i0 + 2 < n) ? deg[i0 + 2] : 0;
    int d3 = (i0 + 3 < n) ? deg[i0 + 3] : 0;
    int s = d0 + d1 + d2 + d3;
    int inc = s;
    for (int o = 1; o < 64; o <<= 1) {
        int u = __shfl_up(inc, o, 64);
        if ((t & 63) >= o) inc += u;
    }
    __shared__ int wt[4];
    if ((t & 63) == 63) wt[t >> 6] = inc;
    __syncthreads();
    int wpre = 0;
    #pragma unroll
    for (int i = 0; i < 4; ++i) wpre += (i < (t >> 6)) ? wt[i] : 0;
    int excl = bsum[blockIdx.x] + wpre + inc - s;
    if (i0     < n) off[i0]     = excl;
    if (i0 + 1 < n) off[i0 + 1] = excl + d0;
    if (i0 + 2 < n) off[i0 + 2] = excl + d0 + d1;
    if (i0 + 3 < n) off[i0 + 3] = excl + d0 + d1 + d2;
}

__global__ __launch_bounds__(256) void fill_kernel(
    const int* __restrict__ src, const int* __restrict__ dst,
    const int* __restrict__ off, int* __restrict__ cursor,
    int* __restrict__ csr_src, int n_edges)
{
    int e = blockIdx.x * 256 + threadIdx.x;
    if (e >= n_edges) return;
    int d = dst[e];
    int pos = off[d] + atomicAdd(&cursor[d], 1);
    csr_src[pos] = src[e];
}

// ============ fused layer: y = ((1+eps)*x + gather-sum) @ W + b ============
// Gather phase: wave w handles rows w, w+4, ...; lane holds float2 of the row.
// GEMM phase: 32-k W panels (16KB) keep LDS at ~49KB -> 3 blocks/CU (12 waves)
// so the latency-heavy gather has threads to hide behind.
__global__ __launch_bounds__(256) void gin_fused(
    const float* __restrict__ xin,
    const int* __restrict__ csr, const int* __restrict__ off,
    const float* __restrict__ W, const float* __restrict__ bias,
    const float* __restrict__ eps, int layer,
    float* __restrict__ y, int n_nodes)
{
    __shared__ float Wl[32 * DIM];          // 16 KB panel, [k][n]
    __shared__ float Hl[ROWS][DIM + HPAD];  // 33.3 KB

    const int t    = threadIdx.x;
    const int r0   = blockIdx.x * ROWS;
    const int wave = t >> 6, lane = t & 63;
    const float e1 = 1.0f + eps[layer];

    // ---- gather H into LDS ----
    for (int rr = wave; rr < ROWS; rr += 4) {
        int r = r0 + rr;
        float2 acc = make_float2(0.f, 0.f);
        if (r < n_nodes) {
            int beg = off[r], end = off[r + 1];
            int k = beg;
            for (; k + 1 < end; k += 2) {
                int s0 = csr[k], s1 = csr[k + 1];
                float2 a = reinterpret_cast<const float2*>(xin + (size_t)s0 * DIM)[lane];
                float2 b = reinterpret_cast<const float2*>(xin + (size_t)s1 * DIM)[lane];
                acc.x += a.x + b.x;
                acc.y += a.y + b.y;
            }
            if (k < end) {
                float2 a = reinterpret_cast<const float2*>(xin + (size_t)csr[k] * DIM)[lane];
                acc.x += a.x;
                acc.y += a.y;
            }
            float2 xv = reinterpret_cast<const float2*>(xin + (size_t)r * DIM)[lane];
            acc.x += e1 * xv.x;
            acc.y += e1 * xv.y;
        }
        reinterpret_cast<float2*>(&Hl[rr][0])[lane] = acc;
    }

    // ---- GEMM ----
    const int rg = t >> 4;   // rows rg*4..rg*4+3
    const int cg = t & 15;   // cols cg*8..cg*8+7
    float acc[4][8];
    #pragma unroll
    for (int i = 0; i < 4; ++i)
        #pragma unroll
        for (int j = 0; j < 8; ++j) acc[i][j] = 0.f;

    for (int kt = 0; kt < 4; ++kt) {
        __syncthreads();   // Hl ready (kt=0) / previous panel consumed
        {
            const float4* W4 = reinterpret_cast<const float4*>(W + (size_t)kt * 32 * DIM);
            float4* Wl4 = reinterpret_cast<float4*>(Wl);
            #pragma unroll
            for (int i = 0; i < 4; ++i) Wl4[t + i * 256] = W4[t + i * 256];
        }
        __syncthreads();

        const int kbase = kt * 32;
        #pragma unroll 4
        for (int k = 0; k < 32; ++k) {
            float4 w0 = reinterpret_cast<float4*>(&Wl[k * DIM])[cg * 2];
            float4 w1 = reinterpret_cast<float4*>(&Wl[k * DIM])[cg * 2 + 1];
            float h0 = Hl[rg * 4 + 0][kbase + k];
            float h1 = Hl[rg * 4 + 1][kbase + k];
            float h2 = Hl[rg * 4 + 2][kbase + k];
            float h3 = Hl[rg * 4 + 3][kbase + k];
            #pragma unroll
            for (int i = 0; i < 4; ++i) {
                float h = (i == 0) ? h0 : (i == 1) ? h1 : (i == 2) ? h2 : h3;
                acc[i][0] += h * w0.x;  acc[i][1] += h * w0.y;
                acc[i][2] += h * w0.z;  acc[i][3] += h * w0.w;
                acc[i][4] += h * w1.x;  acc[i][5] += h * w1.y;
                acc[i][6] += h * w1.z;  acc[i][7] += h * w1.w;
            }
        }
    }

    float4 b0 = reinterpret_cast<const float4*>(bias)[cg * 2];
    float4 b1 = reinterpret_cast<const float4*>(bias)[cg * 2 + 1];
    #pragma unroll
    for (int i = 0; i < 4; ++i) {
        int r = r0 + rg * 4 + i;
        if (r < n_nodes) {
            float4* out = reinterpret_cast<float4*>(y + (size_t)r * DIM + cg * 8);
            out[0] = make_float4(acc[i][0] + b0.x, acc[i][1] + b0.y,
                                 acc[i][2] + b0.z, acc[i][3] + b0.w);
            out[1] = make_float4(acc[i][4] + b1.x, acc[i][5] + b1.y,
                                 acc[i][6] + b1.z, acc[i][7] + b1.w);
        }
    }
}

// ============ head GEMM: out = x @ W_head + b_head (128 -> 40) ============
__global__ __launch_bounds__(256) void head_gemm(
    const float* __restrict__ xin, const float* __restrict__ W,
    const float* __restrict__ bias, float* __restrict__ y, int n_nodes)
{
    __shared__ float Wl[DIM * NOUT];
    __shared__ float Hl[ROWS][DIM + 4];

    const int t  = threadIdx.x;
    const int r0 = blockIdx.x * ROWS;

    for (int i = t; i < DIM * NOUT; i += 256) Wl[i] = W[i];
    {
        int c4 = t & 31;
        for (int rr = t >> 5; rr < ROWS; rr += 8) {
            int r = r0 + rr;
            float4 v = make_float4(0.f, 0.f, 0.f, 0.f);
            if (r < n_nodes)
                v = reinterpret_cast<const float4*>(xin + (size_t)r * DIM)[c4];
            reinterpret_cast<float4*>(&Hl[rr][0])[c4] = v;
        }
    }
    __syncthreads();

    const int row = t >> 2;
    const int cg  = (t & 3) * 10;
    float acc[10];
    #pragma unroll
    for (int j = 0; j < 10; ++j) acc[j] = 0.f;

    #pragma unroll 4
    for (int k = 0; k < DIM; ++k) {
        float h = Hl[row][k];
        #pragma unroll
        for (int j = 0; j < 10; ++j) acc[j] += h * Wl[k * NOUT + cg + j];
    }

    int r = r0 + row;
    if (r < n_nodes) {
        float* out = y + (size_t)r * NOUT + cg;
        #pragma unroll
        for (int j = 0; j < 10; ++j) out[j] = acc[j] + bias[cg + j];
    }
}

extern "C" void kernel_launch(void* const* d_in, const int* in_sizes, int n_in,
                              void* d_out, int out_size, void* d_ws, size_t ws_size,
                              hipStream_t stream) {
    (void)n_in; (void)out_size;
    const float* x    = (const float*)d_in[0];
    const int*   edge = (const int*)d_in[1];
    const float* eps  = (const float*)d_in[2];
    const float* Ws   = (const float*)d_in[3];
    const float* bs   = (const float*)d_in[4];
    const float* Wh   = (const float*)d_in[5];
    const float* bh   = (const float*)d_in[6];

    const int n_nodes = in_sizes[0] / DIM;
    const int n_edges = in_sizes[1] / 2;
    const int* src = edge;
    const int* dst = edge + n_edges;

    const size_t featB = (size_t)n_nodes * DIM * sizeof(float);
    float* bufA = (float*)d_ws;                       // ping
    float* bufB = (float*)((char*)d_ws + featB);      // pong

    const int nscan = (n_nodes + 1023) / 1024;        // scan partial blocks (<=128)
    const size_t extraB = ((size_t)n_nodes + (size_t)(n_nodes + 1)
                           + (size_t)n_edges + 128) * sizeof(int);
    char* extra = (ws_size >= 2 * featB + extraB)
                ? (char*)d_ws + 2 * featB
                : (char*)d_out;   // d_out only written by head at the very end
    int* deg  = (int*)extra;                 // reused as fill-cursor after apply
    int* off  = deg + n_nodes;
    int* csr  = off + n_nodes + 1;
    int* bsum = csr + n_edges;

    const dim3 blk(256);
    const int edge_grid = (n_edges + 255) / 256;
    const int gemm_grid = (n_nodes + ROWS - 1) / ROWS;

    // ---- build CSR once ----
    hipMemsetAsync(deg, 0, (size_t)n_nodes * sizeof(int), stream);
    hist_kernel<<<edge_grid, blk, 0, stream>>>(dst, deg, n_edges);
    reduce_kernel<<<nscan, blk, 0, stream>>>(deg, bsum, n_nodes);
    scan_sums_kernel<<<1, 128, 0, stream>>>(bsum, nscan, off + n_nodes);
    apply_kernel<<<nscan, blk, 0, stream>>>(deg, bsum, off, n_nodes);
    hipMemsetAsync(deg, 0, (size_t)n_nodes * sizeof(int), stream);
    fill_kernel<<<edge_grid, blk, 0, stream>>>(src, dst, off, deg, csr, n_edges);

    // ---- 3 fused GIN layers (ping-pong; fused gather reads foreign rows) ----
    gin_fused<<<gemm_grid, blk, 0, stream>>>(x,    csr, off, Ws,                 bs,           eps, 0, bufA, n_nodes);
    gin_fused<<<gemm_grid, blk, 0, stream>>>(bufA, csr, off, Ws + (size_t)DIM*DIM,   bs + DIM,     eps, 1, bufB, n_nodes);
    gin_fused<<<gemm_grid, blk, 0, stream>>>(bufB, csr, off, Ws + (size_t)2*DIM*DIM, bs + 2*DIM,   eps, 2, bufA, n_nodes);
    head_gemm<<<gemm_grid, blk, 0, stream>>>(bufA, Wh, bh, (float*)d_out, n_nodes);
}

// Round 4
// 285.618 us; speedup vs baseline: 2.1802x; 2.1802x over previous
//
#include <hip/hip_runtime.h>

#define DIM 128
#define NOUT 40

typedef __attribute__((ext_vector_type(8))) short bf16x8_t;
typedef __attribute__((ext_vector_type(4))) float f32x4_t;

__device__ __forceinline__ ushort f2bf(float f) {
    unsigned u = __float_as_uint(f);
    u += 0x7fffu + ((u >> 16) & 1u);          // round-to-nearest-even
    return (ushort)(u >> 16);
}
__device__ __forceinline__ float bflo(unsigned v) { return __uint_as_float(v << 16); }
__device__ __forceinline__ float bfhi(unsigned v) { return __uint_as_float(v & 0xffff0000u); }

// ============ CSR build (unchanged from R3 — fast) ============

__global__ __launch_bounds__(256) void hist_kernel(
    const int* __restrict__ dst, int* __restrict__ deg, int n_edges)
{
    int e = blockIdx.x * 256 + threadIdx.x;
    if (e < n_edges) atomicAdd(&deg[dst[e]], 1);
}

__global__ __launch_bounds__(256) void reduce_kernel(
    const int* __restrict__ deg, int* __restrict__ bsum, int n)
{
    int t = threadIdx.x;
    int base = blockIdx.x * 1024 + t;
    int s = 0;
    #pragma unroll
    for (int i = 0; i < 4; ++i) { int idx = base + i * 256; s += (idx < n) ? deg[idx] : 0; }
    for (int o = 32; o; o >>= 1) s += __shfl_down(s, o, 64);
    __shared__ int l[4];
    if ((t & 63) == 0) l[t >> 6] = s;
    __syncthreads();
    if (t == 0) bsum[blockIdx.x] = l[0] + l[1] + l[2] + l[3];
}

__global__ __launch_bounds__(128) void scan_sums_kernel(
    int* __restrict__ bsum, int nb, int* __restrict__ off_n)
{
    __shared__ int l[128];
    int t = threadIdx.x;
    int c = (nb + 127) >> 7;
    int b = t * c, e = min(b + c, nb);
    int s = 0;
    for (int i = b; i < e; ++i) s += bsum[i];
    l[t] = s;
    __syncthreads();
    for (int d = 1; d < 128; d <<= 1) {
        int u = (t >= d) ? l[t - d] : 0;
        __syncthreads();
        l[t] += u;
        __syncthreads();
    }
    int pre = l[t] - s;
    for (int i = b; i < e; ++i) { int v = bsum[i]; bsum[i] = pre; pre += v; }
    if (t == 127) *off_n = l[127];
}

__global__ __launch_bounds__(256) void apply_kernel(
    const int* __restrict__ deg, const int* __restrict__ bsum,
    int* __restrict__ off, int n)
{
    int t = threadIdx.x;
    int i0 = blockIdx.x * 1024 + t * 4;
    int d0 = (i0     < n) ? deg[i0]     : 0;
    int d1 = (i0 + 1 < n) ? deg[i0 + 1] : 0;
    int d2 = (i0 + 2 < n) ? deg[i0 + 2] : 0;
    int d3 = (i0 + 3 < n) ? deg[i0 + 3] : 0;
    int s = d0 + d1 + d2 + d3;
    int inc = s;
    for (int o = 1; o < 64; o <<= 1) {
        int u = __shfl_up(inc, o, 64);
        if ((t & 63) >= o) inc += u;
    }
    __shared__ int wt[4];
    if ((t & 63) == 63) wt[t >> 6] = inc;
    __syncthreads();
    int wpre = 0;
    #pragma unroll
    for (int i = 0; i < 4; ++i) wpre += (i < (t >> 6)) ? wt[i] : 0;
    int excl = bsum[blockIdx.x] + wpre + inc - s;
    if (i0     < n) off[i0]     = excl;
    if (i0 + 1 < n) off[i0 + 1] = excl + d0;
    if (i0 + 2 < n) off[i0 + 2] = excl + d0 + d1;
    if (i0 + 3 < n) off[i0 + 3] = excl + d0 + d1 + d2;
}

__global__ __launch_bounds__(256) void fill_kernel(
    const int* __restrict__ src, const int* __restrict__ dst,
    const int* __restrict__ off, int* __restrict__ cursor,
    int* __restrict__ csr_src, int n_edges)
{
    int e = blockIdx.x * 256 + threadIdx.x;
    if (e >= n_edges) return;
    int d = dst[e];
    int pos = off[d] + atomicAdd(&cursor[d], 1);
    csr_src[pos] = src[e];
}

// ============ casts / packs ============

__global__ __launch_bounds__(256) void cast_x_kernel(
    const float* __restrict__ x, ushort* __restrict__ xb, int n4)
{
    int i = blockIdx.x * 256 + threadIdx.x;
    if (i >= n4) return;
    float4 v = reinterpret_cast<const float4*>(x)[i];
    reinterpret_cast<ushort4*>(xb)[i] =
        make_ushort4(f2bf(v.x), f2bf(v.y), f2bf(v.z), f2bf(v.w));
}

// Pre-pack W into MFMA B-fragment order: frag f=(ks*NCB+cb), lane l, elem j
// holds W[k= ks*32+(l>>4)*8+j][n= cb*16+(l&15)]  -> B-frag load is 16B/lane contiguous.
__global__ __launch_bounds__(256) void pack_w_kernel(
    const float* __restrict__ Ws, const float* __restrict__ Wh,
    ushort* __restrict__ pW, ushort* __restrict__ pWh)
{
    int tid = blockIdx.x * 256 + threadIdx.x;
    if (tid < 3 * 16384) {                       // 3 layer weights, NCB=8
        int l = tid / 16384, r = tid % 16384;
        int j = r & 7, lane = (r >> 3) & 63, cb = (r >> 9) & 7, ks = r >> 12;
        int k  = ks * 32 + (lane >> 4) * 8 + j;
        int nn = cb * 16 + (lane & 15);
        pW[tid] = f2bf(Ws[(size_t)l * DIM * DIM + (size_t)k * DIM + nn]);
    } else {
        int r = tid - 3 * 16384;                 // head, NCB=3 (cols padded to 48)
        if (r < 4 * 3 * 64 * 8) {
            int j = r & 7, lane = (r >> 3) & 63;
            int rem = r >> 9;                    // 0..11
            int cb = rem % 3, ks = rem / 3;
            int k  = ks * 32 + (lane >> 4) * 8 + j;
            int nn = cb * 16 + (lane & 15);
            pWh[r] = (nn < NOUT) ? f2bf(Wh[(size_t)k * NOUT + nn]) : (ushort)0;
        }
    }
}

// ============ aggregate (bf16): H[i] = (1+eps)*x[i] + sum_j x[csr[j]] ============
// one 64-lane wave per node; lane holds 2 elems (dword); fp32 accum; 4-edge MLP
__global__ __launch_bounds__(256) void agg_bf16_kernel(
    const ushort* __restrict__ xb, const int* __restrict__ csr,
    const int* __restrict__ off, const float* __restrict__ eps, int layer,
    ushort* __restrict__ H, int n_nodes)
{
    int node = blockIdx.x * 4 + (threadIdx.x >> 6);
    if (node >= n_nodes) return;
    int lane = threadIdx.x & 63;
    const float e1 = 1.0f + eps[layer];

    unsigned xv = *reinterpret_cast<const unsigned*>(xb + (size_t)node * DIM + lane * 2);
    float a0 = e1 * bflo(xv);
    float a1 = e1 * bfhi(xv);

    int k = off[node], end = off[node + 1];
    for (; k + 3 < end; k += 4) {
        int s0 = csr[k], s1 = csr[k + 1], s2 = csr[k + 2], s3 = csr[k + 3];
        unsigned v0 = *reinterpret_cast<const unsigned*>(xb + (size_t)s0 * DIM + lane * 2);
        unsigned v1 = *reinterpret_cast<const unsigned*>(xb + (size_t)s1 * DIM + lane * 2);
        unsigned v2 = *reinterpret_cast<const unsigned*>(xb + (size_t)s2 * DIM + lane * 2);
        unsigned v3 = *reinterpret_cast<const unsigned*>(xb + (size_t)s3 * DIM + lane * 2);
        a0 += (bflo(v0) + bflo(v1)) + (bflo(v2) + bflo(v3));
        a1 += (bfhi(v0) + bfhi(v1)) + (bfhi(v2) + bfhi(v3));
    }
    for (; k < end; ++k) {
        unsigned v = *reinterpret_cast<const unsigned*>(xb + (size_t)csr[k] * DIM + lane * 2);
        a0 += bflo(v);
        a1 += bfhi(v);
    }
    *reinterpret_cast<unsigned*>(H + (size_t)node * DIM + lane * 2) =
        (unsigned)f2bf(a0) | ((unsigned)f2bf(a1) << 16);
}

// ============ layer GEMM via MFMA: Y = H @ W + b  (bf16 in, bf16 out) ============
// no LDS; wave owns 16 rows x 128 cols; A from global (16B/lane), B from packed W
__global__ __launch_bounds__(256) void gemm_mfma_kernel(
    const ushort* __restrict__ H, const ushort* __restrict__ pW,
    const float* __restrict__ bias, ushort* __restrict__ Y, int n_nodes)
{
    const int t = threadIdx.x, wave = t >> 6, lane = t & 63;
    const int row16 = blockIdx.x * 64 + wave * 16;
    const int arow  = row16 + (lane & 15);
    const size_t aoff = (size_t)min(arow, n_nodes - 1) * DIM + (lane >> 4) * 8;

    bf16x8_t a0 = *reinterpret_cast<const bf16x8_t*>(H + aoff);
    bf16x8_t a1 = *reinterpret_cast<const bf16x8_t*>(H + aoff + 32);
    bf16x8_t a2 = *reinterpret_cast<const bf16x8_t*>(H + aoff + 64);
    bf16x8_t a3 = *reinterpret_cast<const bf16x8_t*>(H + aoff + 96);

    f32x4_t acc[8];
    #pragma unroll
    for (int cb = 0; cb < 8; ++cb) acc[cb] = (f32x4_t)(0.0f);

    #pragma unroll
    for (int cb = 0; cb < 8; ++cb) {
        const bf16x8_t* bp = reinterpret_cast<const bf16x8_t*>(pW) + cb * 64 + lane;
        bf16x8_t b0 = bp[0];
        bf16x8_t b1 = bp[512];
        bf16x8_t b2 = bp[1024];
        bf16x8_t b3 = bp[1536];
        acc[cb] = __builtin_amdgcn_mfma_f32_16x16x32_bf16(a0, b0, acc[cb], 0, 0, 0);
        acc[cb] = __builtin_amdgcn_mfma_f32_16x16x32_bf16(a1, b1, acc[cb], 0, 0, 0);
        acc[cb] = __builtin_amdgcn_mfma_f32_16x16x32_bf16(a2, b2, acc[cb], 0, 0, 0);
        acc[cb] = __builtin_amdgcn_mfma_f32_16x16x32_bf16(a3, b3, acc[cb], 0, 0, 0);
    }

    const int rbase = row16 + (lane >> 4) * 4;   // C/D: col=lane&15, row=(lane>>4)*4+reg
    #pragma unroll
    for (int cb = 0; cb < 8; ++cb) {
        int col = cb * 16 + (lane & 15);
        float bv = bias[col];
        #pragma unroll
        for (int r = 0; r < 4; ++r) {
            int row = rbase + r;
            if (row < n_nodes) Y[(size_t)row * DIM + col] = f2bf(acc[cb][r] + bv);
        }
    }
}

// ============ head GEMM via MFMA: out = H @ Wh + bh (128 -> 40, fp32 out) ============
__global__ __launch_bounds__(256) void head_mfma_kernel(
    const ushort* __restrict__ H, const ushort* __restrict__ pWh,
    const float* __restrict__ bias, float* __restrict__ out, int n_nodes)
{
    const int t = threadIdx.x, wave = t >> 6, lane = t & 63;
    const int row16 = blockIdx.x * 64 + wave * 16;
    const int arow  = row16 + (lane & 15);
    const size_t aoff = (size_t)min(arow, n_nodes - 1) * DIM + (lane >> 4) * 8;

    bf16x8_t a0 = *reinterpret_cast<const bf16x8_t*>(H + aoff);
    bf16x8_t a1 = *reinterpret_cast<const bf16x8_t*>(H + aoff + 32);
    bf16x8_t a2 = *reinterpret_cast<const bf16x8_t*>(H + aoff + 64);
    bf16x8_t a3 = *reinterpret_cast<const bf16x8_t*>(H + aoff + 96);

    f32x4_t acc[3];
    #pragma unroll
    for (int cb = 0; cb < 3; ++cb) acc[cb] = (f32x4_t)(0.0f);

    #pragma unroll
    for (int cb = 0; cb < 3; ++cb) {
        const bf16x8_t* bp = reinterpret_cast<const bf16x8_t*>(pWh) + cb * 64 + lane;
        bf16x8_t b0 = bp[0];
        bf16x8_t b1 = bp[192];
        bf16x8_t b2 = bp[384];
        bf16x8_t b3 = bp[576];
        acc[cb] = __builtin_amdgcn_mfma_f32_16x16x32_bf16(a0, b0, acc[cb], 0, 0, 0);
        acc[cb] = __builtin_amdgcn_mfma_f32_16x16x32_bf16(a1, b1, acc[cb], 0, 0, 0);
        acc[cb] = __builtin_amdgcn_mfma_f32_16x16x32_bf16(a2, b2, acc[cb], 0, 0, 0);
        acc[cb] = __builtin_amdgcn_mfma_f32_16x16x32_bf16(a3, b3, acc[cb], 0, 0, 0);
    }

    const int rbase = row16 + (lane >> 4) * 4;
    #pragma unroll
    for (int cb = 0; cb < 3; ++cb) {
        int col = cb * 16 + (lane & 15);
        if (col >= NOUT) continue;
        float bv = bias[col];
        #pragma unroll
        for (int r = 0; r < 4; ++r) {
            int row = rbase + r;
            if (row < n_nodes) out[(size_t)row * NOUT + col] = acc[cb][r] + bv;
        }
    }
}

extern "C" void kernel_launch(void* const* d_in, const int* in_sizes, int n_in,
                              void* d_out, int out_size, void* d_ws, size_t ws_size,
                              hipStream_t stream) {
    (void)n_in; (void)out_size; (void)ws_size;
    const float* x    = (const float*)d_in[0];
    const int*   edge = (const int*)d_in[1];
    const float* eps  = (const float*)d_in[2];
    const float* Ws   = (const float*)d_in[3];
    const float* bs   = (const float*)d_in[4];
    const float* Wh   = (const float*)d_in[5];
    const float* bh   = (const float*)d_in[6];

    const int n_nodes = in_sizes[0] / DIM;
    const int n_edges = in_sizes[1] / 2;
    const int* src = edge;
    const int* dst = edge + n_edges;

    // ws layout: buf0 (25.6MB bf16 features) | buf1 (25.6MB bf16 H) | CSR ints | packed W
    // total ~56.5 MB; ws_size >= 102.4 MB (proven by R1 which used that unconditionally)
    const size_t halfE = (size_t)n_nodes * DIM;          // elements
    ushort* buf0 = (ushort*)d_ws;
    ushort* buf1 = buf0 + halfE;
    char* p = (char*)(buf1 + halfE);
    int* deg  = (int*)p;            p += (size_t)n_nodes * 4;
    int* off  = (int*)p;            p += ((size_t)n_nodes + 1) * 4;
    int* bsum = (int*)p;            p += 512;
    int* csr  = (int*)p;            p += (size_t)n_edges * 4;
    p = (char*)(((uintptr_t)p + 15) & ~(uintptr_t)15);
    ushort* pW  = (ushort*)p;       p += 3 * 16384 * 2;
    ushort* pWh = (ushort*)p;

    const dim3 blk(256);
    const int edge_grid = (n_edges + 255) / 256;
    const int node4_grid = (n_nodes + 3) / 4;
    const int gemm_grid = (n_nodes + 63) / 64;
    const int nscan = (n_nodes + 1023) / 1024;
    const int cast_n4 = n_nodes * DIM / 4;

    // ---- CSR build (once) ----
    hipMemsetAsync(deg, 0, (size_t)n_nodes * sizeof(int), stream);
    hist_kernel<<<edge_grid, blk, 0, stream>>>(dst, deg, n_edges);
    reduce_kernel<<<nscan, blk, 0, stream>>>(deg, bsum, n_nodes);
    scan_sums_kernel<<<1, 128, 0, stream>>>(bsum, nscan, off + n_nodes);
    apply_kernel<<<nscan, blk, 0, stream>>>(deg, bsum, off, n_nodes);
    hipMemsetAsync(deg, 0, (size_t)n_nodes * sizeof(int), stream);
    fill_kernel<<<edge_grid, blk, 0, stream>>>(src, dst, off, deg, csr, n_edges);

    // ---- casts / packs ----
    cast_x_kernel<<<(cast_n4 + 255) / 256, blk, 0, stream>>>(x, buf0, cast_n4);
    pack_w_kernel<<<(3 * 16384 + 4 * 3 * 64 * 8 + 255) / 256, blk, 0, stream>>>(Ws, Wh, pW, pWh);

    // ---- 3 GIN layers: agg (buf0 -> buf1), gemm (buf1 -> buf0) ----
    for (int l = 0; l < 3; ++l) {
        agg_bf16_kernel<<<node4_grid, blk, 0, stream>>>(buf0, csr, off, eps, l, buf1, n_nodes);
        gemm_mfma_kernel<<<gemm_grid, blk, 0, stream>>>(
            buf1, pW + (size_t)l * 16384, bs + (size_t)l * DIM, buf0, n_nodes);
    }

    // ---- head ----
    head_mfma_kernel<<<gemm_grid, blk, 0, stream>>>(buf0, pWh, bh, (float*)d_out, n_nodes);
}

// Round 5
// 222.769 us; speedup vs baseline: 2.7953x; 1.2821x over previous
//
#include <hip/hip_runtime.h>

#define DIM 128
#define NOUT 40

typedef __attribute__((ext_vector_type(8))) short bf16x8_t;
typedef __attribute__((ext_vector_type(4))) float f32x4_t;
typedef __attribute__((ext_vector_type(4))) unsigned u32x4_t;

__device__ __forceinline__ ushort f2bf(float f) {
    unsigned u = __float_as_uint(f);
    u += 0x7fffu + ((u >> 16) & 1u);          // round-to-nearest-even
    return (ushort)(u >> 16);
}

// ============ CSR build (unchanged — verified fast) ============

__global__ __launch_bounds__(256) void hist_kernel(
    const int* __restrict__ dst, int* __restrict__ deg, int n_edges)
{
    int e = blockIdx.x * 256 + threadIdx.x;
    if (e < n_edges) atomicAdd(&deg[dst[e]], 1);
}

__global__ __launch_bounds__(256) void reduce_kernel(
    const int* __restrict__ deg, int* __restrict__ bsum, int n)
{
    int t = threadIdx.x;
    int base = blockIdx.x * 1024 + t;
    int s = 0;
    #pragma unroll
    for (int i = 0; i < 4; ++i) { int idx = base + i * 256; s += (idx < n) ? deg[idx] : 0; }
    for (int o = 32; o; o >>= 1) s += __shfl_down(s, o, 64);
    __shared__ int l[4];
    if ((t & 63) == 0) l[t >> 6] = s;
    __syncthreads();
    if (t == 0) bsum[blockIdx.x] = l[0] + l[1] + l[2] + l[3];
}

__global__ __launch_bounds__(128) void scan_sums_kernel(
    int* __restrict__ bsum, int nb, int* __restrict__ off_n)
{
    __shared__ int l[128];
    int t = threadIdx.x;
    int c = (nb + 127) >> 7;
    int b = t * c, e = min(b + c, nb);
    int s = 0;
    for (int i = b; i < e; ++i) s += bsum[i];
    l[t] = s;
    __syncthreads();
    for (int d = 1; d < 128; d <<= 1) {
        int u = (t >= d) ? l[t - d] : 0;
        __syncthreads();
        l[t] += u;
        __syncthreads();
    }
    int pre = l[t] - s;
    for (int i = b; i < e; ++i) { int v = bsum[i]; bsum[i] = pre; pre += v; }
    if (t == 127) *off_n = l[127];
}

__global__ __launch_bounds__(256) void apply_kernel(
    const int* __restrict__ deg, const int* __restrict__ bsum,
    int* __restrict__ off, int n)
{
    int t = threadIdx.x;
    int i0 = blockIdx.x * 1024 + t * 4;
    int d0 = (i0     < n) ? deg[i0]     : 0;
    int d1 = (i0 + 1 < n) ? deg[i0 + 1] : 0;
    int d2 = (i0 + 2 < n) ? deg[i0 + 2] : 0;
    int d3 = (i0 + 3 < n) ? deg[i0 + 3] : 0;
    int s = d0 + d1 + d2 + d3;
    int inc = s;
    for (int o = 1; o < 64; o <<= 1) {
        int u = __shfl_up(inc, o, 64);
        if ((t & 63) >= o) inc += u;
    }
    __shared__ int wt[4];
    if ((t & 63) == 63) wt[t >> 6] = inc;
    __syncthreads();
    int wpre = 0;
    #pragma unroll
    for (int i = 0; i < 4; ++i) wpre += (i < (t >> 6)) ? wt[i] : 0;
    int excl = bsum[blockIdx.x] + wpre + inc - s;
    if (i0     < n) off[i0]     = excl;
    if (i0 + 1 < n) off[i0 + 1] = excl + d0;
    if (i0 + 2 < n) off[i0 + 2] = excl + d0 + d1;
    if (i0 + 3 < n) off[i0 + 3] = excl + d0 + d1 + d2;
}

__global__ __launch_bounds__(256) void fill_kernel(
    const int* __restrict__ src, const int* __restrict__ dst,
    const int* __restrict__ off, int* __restrict__ cursor,
    int* __restrict__ csr_src, int n_edges)
{
    int e = blockIdx.x * 256 + threadIdx.x;
    if (e >= n_edges) return;
    int d = dst[e];
    int pos = off[d] + atomicAdd(&cursor[d], 1);
    csr_src[pos] = src[e];
}

// ============ casts / packs (unchanged) ============

__global__ __launch_bounds__(256) void cast_x_kernel(
    const float* __restrict__ x, ushort* __restrict__ xb, int n4)
{
    int i = blockIdx.x * 256 + threadIdx.x;
    if (i >= n4) return;
    float4 v = reinterpret_cast<const float4*>(x)[i];
    reinterpret_cast<ushort4*>(xb)[i] =
        make_ushort4(f2bf(v.x), f2bf(v.y), f2bf(v.z), f2bf(v.w));
}

// B-frag pack: frag f=(ks*NCB+cb), lane l, elem j holds W[ks*32+(l>>4)*8+j][cb*16+(l&15)]
__global__ __launch_bounds__(256) void pack_w_kernel(
    const float* __restrict__ Ws, const float* __restrict__ Wh,
    ushort* __restrict__ pW, ushort* __restrict__ pWh)
{
    int tid = blockIdx.x * 256 + threadIdx.x;
    if (tid < 3 * 16384) {                       // 3 layer weights, NCB=8
        int l = tid / 16384, r = tid % 16384;
        int j = r & 7, lane = (r >> 3) & 63, cb = (r >> 9) & 7, ks = r >> 12;
        int k  = ks * 32 + (lane >> 4) * 8 + j;
        int nn = cb * 16 + (lane & 15);
        pW[tid] = f2bf(Ws[(size_t)l * DIM * DIM + (size_t)k * DIM + nn]);
    } else {
        int r = tid - 3 * 16384;                 // head, NCB=3 (cols padded to 48)
        if (r < 4 * 3 * 64 * 8) {
            int j = r & 7, lane = (r >> 3) & 63;
            int rem = r >> 9;
            int cb = rem % 3, ks = rem / 3;
            int k  = ks * 32 + (lane >> 4) * 8 + j;
            int nn = cb * 16 + (lane & 15);
            pWh[r] = (nn < NOUT) ? f2bf(Wh[(size_t)k * NOUT + nn]) : (ushort)0;
        }
    }
}

// ============ fused layer: gather H straight into A-frags, MFMA, pack-store ============
// Wave owns 16 nodes (rows). Lane l: row = l&15, k-segment kseg=(l>>4)*8 within each
// 32-k block -> gathers its A-fragment elements directly (fp32 accum), converts to
// bf16 frags, runs 32 MFMAs against pre-packed W, stages C in LDS for coalesced
// 16B stores.  HEAD variant chains the 128->40 head GEMM off the LDS tile instead
// of writing features.
template<bool HEAD>
__global__ __launch_bounds__(256) void gin_fused_mfma(
    const ushort* __restrict__ xb,
    const int* __restrict__ csr, const int* __restrict__ off,
    const ushort* __restrict__ pW, const float* __restrict__ bias,
    const ushort* __restrict__ pWh, const float* __restrict__ bh,
    const float* __restrict__ eps, int layer,
    ushort* __restrict__ Y, float* __restrict__ out, int n_nodes)
{
    __shared__ ushort lds[4][16][136];   // stride 272B: 16B-aligned rows, ~2-way max conflict

    const int t = threadIdx.x, wave = t >> 6, lane = t & 63;
    const int rloc = lane & 15;          // row within this wave's 16-row tile
    const int kseg = lane >> 4;          // 0..3
    const int row16 = blockIdx.x * 64 + wave * 16;
    const int node  = row16 + rloc;
    const int nclamp = min(node, n_nodes - 1);
    const float e1 = 1.0f + eps[layer];

    // ---- gather: a[s][j] accumulates H[row][s*32 + kseg*8 + j] in fp32 ----
    float a[4][8];
    {
        const ushort* xr = xb + (size_t)nclamp * DIM + kseg * 8;
        #pragma unroll
        for (int s = 0; s < 4; ++s) {
            u32x4_t v = *reinterpret_cast<const u32x4_t*>(xr + s * 32);
            #pragma unroll
            for (int q = 0; q < 4; ++q) {
                a[s][2*q]   = e1 * __uint_as_float(v[q] << 16);
                a[s][2*q+1] = e1 * __uint_as_float(v[q] & 0xffff0000u);
            }
        }
    }
    int k = off[nclamp], ke = off[nclamp + 1];
    for (; k + 1 < ke; k += 2) {
        const ushort* r0 = xb + (size_t)csr[k]     * DIM + kseg * 8;
        const ushort* r1 = xb + (size_t)csr[k + 1] * DIM + kseg * 8;
        u32x4_t u0[4], u1[4];
        #pragma unroll
        for (int s = 0; s < 4; ++s) u0[s] = *reinterpret_cast<const u32x4_t*>(r0 + s * 32);
        #pragma unroll
        for (int s = 0; s < 4; ++s) u1[s] = *reinterpret_cast<const u32x4_t*>(r1 + s * 32);
        #pragma unroll
        for (int s = 0; s < 4; ++s)
            #pragma unroll
            for (int q = 0; q < 4; ++q) {
                a[s][2*q]   += __uint_as_float(u0[s][q] << 16)
                             + __uint_as_float(u1[s][q] << 16);
                a[s][2*q+1] += __uint_as_float(u0[s][q] & 0xffff0000u)
                             + __uint_as_float(u1[s][q] & 0xffff0000u);
            }
    }
    if (k < ke) {
        const ushort* r0 = xb + (size_t)csr[k] * DIM + kseg * 8;
        #pragma unroll
        for (int s = 0; s < 4; ++s) {
            u32x4_t v = *reinterpret_cast<const u32x4_t*>(r0 + s * 32);
            #pragma unroll
            for (int q = 0; q < 4; ++q) {
                a[s][2*q]   += __uint_as_float(v[q] << 16);
                a[s][2*q+1] += __uint_as_float(v[q] & 0xffff0000u);
            }
        }
    }

    // ---- convert to bf16 A-frags ----
    bf16x8_t af[4];
    #pragma unroll
    for (int s = 0; s < 4; ++s)
        #pragma unroll
        for (int j = 0; j < 8; ++j) af[s][j] = (short)f2bf(a[s][j]);

    // ---- layer GEMM: 8 col-blocks x 4 k-steps, bias preloaded into acc ----
    const bf16x8_t* pw8 = reinterpret_cast<const bf16x8_t*>(pW);
    f32x4_t acc[8];
    #pragma unroll
    for (int cb = 0; cb < 8; ++cb) acc[cb] = (f32x4_t)(bias[cb * 16 + rloc]);
    #pragma unroll
    for (int cb = 0; cb < 8; ++cb) {
        const bf16x8_t* bp = pw8 + cb * 64 + lane;
        acc[cb] = __builtin_amdgcn_mfma_f32_16x16x32_bf16(af[0], bp[0],    acc[cb], 0, 0, 0);
        acc[cb] = __builtin_amdgcn_mfma_f32_16x16x32_bf16(af[1], bp[512],  acc[cb], 0, 0, 0);
        acc[cb] = __builtin_amdgcn_mfma_f32_16x16x32_bf16(af[2], bp[1024], acc[cb], 0, 0, 0);
        acc[cb] = __builtin_amdgcn_mfma_f32_16x16x32_bf16(af[3], bp[1536], acc[cb], 0, 0, 0);
    }

    // ---- stage C tile in LDS (C/D: col=lane&15, row=(lane>>4)*4+reg) ----
    #pragma unroll
    for (int cb = 0; cb < 8; ++cb)
        #pragma unroll
        for (int r = 0; r < 4; ++r)
            lds[wave][kseg * 4 + r][cb * 16 + rloc] = f2bf(acc[cb][r]);
    __syncthreads();

    if (!HEAD) {
        // coalesced feature store: 4 passes, lane reads/writes 16B
        #pragma unroll
        for (int p = 0; p < 4; ++p) {
            int rl = p * 4 + kseg;
            int row = row16 + rl;
            bf16x8_t v = *reinterpret_cast<const bf16x8_t*>(&lds[wave][rl][rloc * 8]);
            if (row < n_nodes)
                *reinterpret_cast<bf16x8_t*>(Y + (size_t)row * DIM + rloc * 8) = v;
        }
    } else {
        // head GEMM chained off the LDS tile: A-frags re-read per frag layout
        bf16x8_t hf[4];
        #pragma unroll
        for (int s = 0; s < 4; ++s)
            hf[s] = *reinterpret_cast<const bf16x8_t*>(&lds[wave][rloc][s * 32 + kseg * 8]);
        const bf16x8_t* ph8 = reinterpret_cast<const bf16x8_t*>(pWh);
        f32x4_t hacc[3];
        #pragma unroll
        for (int cb = 0; cb < 3; ++cb) {
            int col = cb * 16 + rloc;
            hacc[cb] = (f32x4_t)((col < NOUT) ? bh[col] : 0.f);
            const bf16x8_t* bp = ph8 + cb * 64 + lane;
            hacc[cb] = __builtin_amdgcn_mfma_f32_16x16x32_bf16(hf[0], bp[0],   hacc[cb], 0, 0, 0);
            hacc[cb] = __builtin_amdgcn_mfma_f32_16x16x32_bf16(hf[1], bp[192], hacc[cb], 0, 0, 0);
            hacc[cb] = __builtin_amdgcn_mfma_f32_16x16x32_bf16(hf[2], bp[384], hacc[cb], 0, 0, 0);
            hacc[cb] = __builtin_amdgcn_mfma_f32_16x16x32_bf16(hf[3], bp[576], hacc[cb], 0, 0, 0);
        }
        #pragma unroll
        for (int cb = 0; cb < 3; ++cb) {
            int col = cb * 16 + rloc;
            if (col < NOUT) {
                #pragma unroll
                for (int r = 0; r < 4; ++r) {
                    int row = row16 + kseg * 4 + r;
                    if (row < n_nodes) out[(size_t)row * NOUT + col] = hacc[cb][r];
                }
            }
        }
    }
}

extern "C" void kernel_launch(void* const* d_in, const int* in_sizes, int n_in,
                              void* d_out, int out_size, void* d_ws, size_t ws_size,
                              hipStream_t stream) {
    (void)n_in; (void)out_size; (void)ws_size;
    const float* x    = (const float*)d_in[0];
    const int*   edge = (const int*)d_in[1];
    const float* eps  = (const float*)d_in[2];
    const float* Ws   = (const float*)d_in[3];
    const float* bs   = (const float*)d_in[4];
    const float* Wh   = (const float*)d_in[5];
    const float* bh   = (const float*)d_in[6];

    const int n_nodes = in_sizes[0] / DIM;
    const int n_edges = in_sizes[1] / 2;
    const int* src = edge;
    const int* dst = edge + n_edges;

    const size_t halfE = (size_t)n_nodes * DIM;          // elements
    ushort* buf0 = (ushort*)d_ws;
    ushort* buf1 = buf0 + halfE;
    char* p = (char*)(buf1 + halfE);
    int* deg  = (int*)p;            p += (size_t)n_nodes * 4;
    int* off  = (int*)p;            p += ((size_t)n_nodes + 1) * 4;
    int* bsum = (int*)p;            p += 512;
    int* csr  = (int*)p;            p += (size_t)n_edges * 4;
    p = (char*)(((uintptr_t)p + 15) & ~(uintptr_t)15);
    ushort* pW  = (ushort*)p;       p += 3 * 16384 * 2;
    ushort* pWh = (ushort*)p;

    const dim3 blk(256);
    const int edge_grid  = (n_edges + 255) / 256;
    const int fused_grid = (n_nodes + 63) / 64;
    const int nscan = (n_nodes + 1023) / 1024;
    const int cast_n4 = n_nodes * DIM / 4;

    // ---- CSR build (once) ----
    hipMemsetAsync(deg, 0, (size_t)n_nodes * sizeof(int), stream);
    hist_kernel<<<edge_grid, blk, 0, stream>>>(dst, deg, n_edges);
    reduce_kernel<<<nscan, blk, 0, stream>>>(deg, bsum, n_nodes);
    scan_sums_kernel<<<1, 128, 0, stream>>>(bsum, nscan, off + n_nodes);
    apply_kernel<<<nscan, blk, 0, stream>>>(deg, bsum, off, n_nodes);
    hipMemsetAsync(deg, 0, (size_t)n_nodes * sizeof(int), stream);
    fill_kernel<<<edge_grid, blk, 0, stream>>>(src, dst, off, deg, csr, n_edges);

    // ---- casts / packs ----
    cast_x_kernel<<<(cast_n4 + 255) / 256, blk, 0, stream>>>(x, buf0, cast_n4);
    pack_w_kernel<<<(3 * 16384 + 4 * 3 * 64 * 8 + 255) / 256, blk, 0, stream>>>(Ws, Wh, pW, pWh);

    // ---- 3 fused layers; layer 2 chains the head ----
    gin_fused_mfma<false><<<fused_grid, blk, 0, stream>>>(
        buf0, csr, off, pW,          bs,           pWh, bh, eps, 0, buf1, nullptr, n_nodes);
    gin_fused_mfma<false><<<fused_grid, blk, 0, stream>>>(
        buf1, csr, off, pW + 16384,  bs + DIM,     pWh, bh, eps, 1, buf0, nullptr, n_nodes);
    gin_fused_mfma<true><<<fused_grid, blk, 0, stream>>>(
        buf0, csr, off, pW + 32768,  bs + 2 * DIM, pWh, bh, eps, 2, nullptr, (float*)d_out, n_nodes);
}